// Round 3
// baseline (906.035 us; speedup 1.0000x reference)
//
#include <hip/hip_runtime.h>
#include <hip/hip_bf16.h>
#include <cstdint>
#include <cstddef>

// S4D-PLR transition model, MI355X (gfx950).
// R2: barrier-free register GEMM. MFMA fragments loaded straight from global
// (A[row,K] / B^T[row,K], lane pattern row=l&15, k=quad*8) with 1-deep
// register prefetch. No LDS, no barriers, no DMA staging -> waves fully
// independent, latency hidden by ~12 waves/CU + compiler load scheduling.

typedef __bf16 bf16;
typedef __bf16 bf16x8 __attribute__((ext_vector_type(8)));
typedef __bf16 bf16x4 __attribute__((ext_vector_type(4)));
typedef float f32x4 __attribute__((ext_vector_type(4)));

// ---------------------------------------------------------------- tile map
// XCD-aware: blocks L%8 -> XCD; consecutive s=L/8 on one XCD sweep all 16
// m-tiles of one n-tile (B-tile stays in that XCD's L2).
__device__ __forceinline__ bool tile_map(int NT, int& m0, int& n0) {
  int L = blockIdx.x;
  int x = L & 7, s = L >> 3;
  int nt = ((s >> 4) << 3) + x;
  if (nt >= NT) return false;
  n0 = nt << 7;
  m0 = (s & 15) << 7;
  return true;
}

// ---------------------------------------------------------------- GEMM core
// C[128x128] = A[128x512] * Bw^T (Bw [N,512] bf16, k-contiguous).
// 4 waves (2x2), each 64x64 via 4x4 mfma_f32_16x16x32_bf16. Fragments loaded
// directly global->VGPR; register double-buffer, fully unrolled K.
__device__ __forceinline__ void gemm_direct(const bf16* __restrict__ A,
                                            const bf16* __restrict__ Bw,
                                            int m0, int n0, f32x4 acc[4][4]) {
  const int l = threadIdx.x & 63, w = threadIdx.x >> 6;
  const int wm = (w >> 1) << 6, wn = (w & 1) << 6;
  const int fr = l & 15, q = l >> 4;
  const bf16* ap = A + (size_t)(m0 + wm + fr) * 512 + (q << 3);
  const bf16* bp = Bw + (size_t)(n0 + wn + fr) * 512 + (q << 3);
#pragma unroll
  for (int mt = 0; mt < 4; ++mt)
#pragma unroll
    for (int nt = 0; nt < 4; ++nt) { f32x4 z = {0.f, 0.f, 0.f, 0.f}; acc[mt][nt] = z; }
  bf16x8 af[2][4], bfv[2][4];
#pragma unroll
  for (int mt = 0; mt < 4; ++mt) af[0][mt] = *(const bf16x8*)(ap + mt * 8192);
#pragma unroll
  for (int nt = 0; nt < 4; ++nt) bfv[0][nt] = *(const bf16x8*)(bp + nt * 8192);
#pragma unroll
  for (int kt = 0; kt < 16; ++kt) {
    const int c = kt & 1, nx = c ^ 1;
    if (kt < 15) {
      const int ko = (kt + 1) << 5;
#pragma unroll
      for (int mt = 0; mt < 4; ++mt) af[nx][mt] = *(const bf16x8*)(ap + ko + mt * 8192);
#pragma unroll
      for (int nt = 0; nt < 4; ++nt) bfv[nx][nt] = *(const bf16x8*)(bp + ko + nt * 8192);
    }
#pragma unroll
    for (int mt = 0; mt < 4; ++mt)
#pragma unroll
      for (int nt = 0; nt < 4; ++nt)
        acc[mt][nt] = __builtin_amdgcn_mfma_f32_16x16x32_bf16(af[c][mt], bfv[c][nt],
                                                              acc[mt][nt], 0, 0, 0);
  }
}
// C/D layout (verified m89/m91): col = lane&15, row = (lane>>4)*4 + reg.

// ---------------------------------------------------------------- weight transpose
// All segments: K = 512, N multiple of 64 -> no guards needed.
struct TEntry { const float* src; bf16* dst; int N, tile0, ntn; };
struct TArgs { TEntry e[11]; };

__global__ void k_transpose(TArgs a) {
  __shared__ float tile[64][65];
  int t = blockIdx.x;
  int ei = 0;
  while (ei < 10 && t >= a.e[ei + 1].tile0) ++ei;
  const TEntry E = a.e[ei];
  int lt = t - E.tile0;
  int tk = lt / E.ntn, tn = lt - tk * E.ntn;
  int k0 = tk << 6, n0 = tn << 6;
  int tid = threadIdx.x;
#pragma unroll
  for (int i = 0; i < 4; ++i) {
    int idx = tid + i * 256;                // 1024 float4 chunks
    int kk = idx >> 4, c4 = (idx & 15) << 2;
    const float4 v = *(const float4*)(E.src + (size_t)(k0 + kk) * E.N + n0 + c4);
    tile[c4 + 0][kk] = v.x; tile[c4 + 1][kk] = v.y;
    tile[c4 + 2][kk] = v.z; tile[c4 + 3][kk] = v.w;
  }
  __syncthreads();
#pragma unroll
  for (int i = 0; i < 4; ++i) {
    int idx = tid + i * 256;
    int nn = idx >> 4, k4 = (idx & 15) << 2;
    bf16x4 o;
    o[0] = (bf16)tile[nn][k4 + 0]; o[1] = (bf16)tile[nn][k4 + 1];
    o[2] = (bf16)tile[nn][k4 + 2]; o[3] = (bf16)tile[nn][k4 + 3];
    *(bf16x4*)(E.dst + (size_t)(n0 + nn) * 512 + k0 + k4) = o;
  }
}

// ---------------------------------------------------------------- bias gather
__global__ void k_prep(const float* ba, const float* bo, const float* bVr, const float* bVi,
                       const float* bBr, const float* bBi, const float* bD,
                       const float* bUr, const float* bUi, const float* bCr, const float* bCi,
                       float* bbigA, float* bbigB, float* bbigC) {
  int i = blockIdx.x * 256 + threadIdx.x;
  if (i < 22656) {
    float v;
    if (i < 256) v = ba[i];
    else if (i < 512) v = bo[i - 256];
    else if (i < 2560) v = bVr[i - 512];
    else if (i < 4608) v = bVi[i - 2560];
    else if (i < 12800) v = bBr[i - 4608];
    else if (i < 20992) v = bBi[i - 12800];
    else if (i < 22592) v = bD[i - 20992];
    else v = 0.f;
    bbigA[i] = v;
  }
  int j = i - 22656;
  if (j >= 0 && j < 4096) bbigB[j] = (j < 2048) ? bUr[j] : bUi[j - 2048];
  int m = i - (22656 + 4096);
  if (m >= 0 && m < 25600) bbigC[m] = (m < 12800) ? bCr[m] : bCi[m - 12800];
}

// ---------------------------------------------------------------- selector MLP (fp32)
__global__ void k_lin0(const float* __restrict__ zt, const float* __restrict__ dt,
                       const float* __restrict__ ut, const float* __restrict__ W0,
                       const float* __restrict__ b0, float* __restrict__ s0) {
  int i = blockIdx.x * 256 + threadIdx.x;      // 2048*128
  int b = i >> 7, c = i & 127;
  const float* w = W0 + c;
  const float* x = zt + (size_t)b * 512;
  float acc = b0[c];
#pragma unroll 4
  for (int k = 0; k < 512; ++k) acc = fmaf(x[k], w[(size_t)k * 128], acc);
  const float* u = ut + (size_t)b * 32;
#pragma unroll
  for (int k = 0; k < 32; ++k) acc = fmaf(u[k], w[(size_t)(512 + k) * 128], acc);
  acc = fmaf(dt[b], w[(size_t)544 * 128], acc);
  s0[i] = acc;
}

__global__ void k_stats(const float* __restrict__ s, float* __restrict__ mu,
                        float* __restrict__ rstd) {
  int c = blockIdx.x;                           // 128 columns
  float sm = 0.f, sq = 0.f;
  for (int r = threadIdx.x; r < 2048; r += 256) {
    float v = s[(size_t)r * 128 + c];
    sm += v; sq += v * v;
  }
#pragma unroll
  for (int o = 32; o >= 1; o >>= 1) { sm += __shfl_down(sm, o); sq += __shfl_down(sq, o); }
  __shared__ float red[8];
  int w = threadIdx.x >> 6;
  if ((threadIdx.x & 63) == 0) { red[w] = sm; red[4 + w] = sq; }
  __syncthreads();
  if (threadIdx.x == 0) {
    float S = red[0] + red[1] + red[2] + red[3];
    float Q = red[4] + red[5] + red[6] + red[7];
    float m = S * (1.f / 2048.f);
    float var = Q * (1.f / 2048.f) - m * m;    // biased var (training-mode BN)
    mu[c] = m;
    rstd[c] = rsqrtf(var + 1e-5f);
  }
}

__global__ void k_lin1(const float* __restrict__ s0, const float* __restrict__ mu,
                       const float* __restrict__ rstd, const float* __restrict__ g,
                       const float* __restrict__ be, const float* __restrict__ W1,
                       const float* __restrict__ b1, float* __restrict__ s1) {
  int i = blockIdx.x * 256 + threadIdx.x;      // 2048*128
  int b = i >> 7, c = i & 127;
  const float* w = W1 + c;
  const float* x = s0 + (size_t)b * 128;
  float acc = b1[c];
#pragma unroll 4
  for (int k = 0; k < 128; ++k) {
    float h = fmaxf(fmaf((x[k] - mu[k]) * rstd[k], g[k], be[k]), 0.f);
    acc = fmaf(h, w[(size_t)k * 128], acc);
  }
  s1[i] = acc;
}

__global__ void k_lin2(const float* __restrict__ s1, const float* __restrict__ mu,
                       const float* __restrict__ rstd, const float* __restrict__ g,
                       const float* __restrict__ be, const float* __restrict__ W2,
                       const float* __restrict__ b2, bf16* __restrict__ hz) {
  int i = blockIdx.x * 256 + threadIdx.x;      // 2048*512
  int b = i >> 9, c = i & 511;
  const float* w = W2 + c;
  const float* x = s1 + (size_t)b * 128;
  float acc = b2[c];
#pragma unroll 4
  for (int k = 0; k < 128; ++k) {
    float h = fmaxf(fmaf((x[k] - mu[k]) * rstd[k], g[k], be[k]), 0.f);
    acc = fmaf(h, w[(size_t)k * 512], acc);
  }
  hz[i] = (bf16)acc;
}

// ---------------------------------------------------------------- phase A GEMM
// columns: [0,256) a | [256,512) o | [512,2560) Vr | [2560,4608) Vi
//          [4608,12800) Br | [12800,20992) Bi | [20992,22592) D | pad to 22656
__global__ __launch_bounds__(256, 3) void k_gemmA(
    const bf16* __restrict__ hz, const bf16* __restrict__ WT, const float* __restrict__ bias,
    const float* __restrict__ zt, const float* __restrict__ dt, const float* __restrict__ ut,
    float* __restrict__ pa, float* __restrict__ po,
    float* __restrict__ Bzr, float* __restrict__ Bzi,
    float* __restrict__ tbuf, float* __restrict__ ytout) {
  int m0, n0;
  if (!tile_map(177, m0, n0)) return;
  f32x4 acc[4][4];
  gemm_direct(hz, WT, m0, n0, acc);
  const int l = threadIdx.x & 63, w = threadIdx.x >> 6;
  const int wm = (w >> 1) << 6, wn = (w & 1) << 6;
  const int fr = l & 15, quad = l >> 4;
  const int ncol = n0 + wn;

  if (n0 < 512) {                                    // ---- a / o pre-acts
    float* dst = (n0 < 256) ? pa : po;
    int cb = ncol - ((n0 < 256) ? 0 : 256);
#pragma unroll
    for (int mt = 0; mt < 4; ++mt)
#pragma unroll
      for (int j = 0; j < 4; ++j) {
        int b = m0 + wm + mt * 16 + quad * 4 + j;
#pragma unroll
        for (int nt = 0; nt < 4; ++nt) {
          int n = ncol + nt * 16 + fr;
          dst[(size_t)b * 256 + (cb + nt * 16 + fr)] = acc[mt][nt][j] + bias[n];
        }
      }
  } else if (n0 < 4608) {                            // ---- V: t = conj(V)^T z
    const bool isVr = n0 < 2560;
#pragma unroll
    for (int mt = 0; mt < 4; ++mt)
#pragma unroll
      for (int j = 0; j < 4; ++j) {
        int b = m0 + wm + mt * 16 + quad * 4 + j;
        float cre = 0.f, cim = 0.f;
#pragma unroll
        for (int nt = 0; nt < 4; ++nt) {
          int n = ncol + nt * 16 + fr;
          float v = acc[mt][nt][j] + bias[n];
          int d = ((n - 512) & 2047) >> 3;
          float zr = zt[(size_t)b * 512 + d], zi = zt[(size_t)b * 512 + 256 + d];
          if (isVr) { cre += v * zr; cim += v * zi; }
          else      { cre += v * zi; cim -= v * zr; }
        }
        cre += __shfl_xor(cre, 8);
        cim += __shfl_xor(cim, 8);
        if ((l & 8) == 0) {
          int r = fr & 7;
          atomicAdd(&tbuf[((size_t)b * 8 + r) * 2 + 0], cre);
          atomicAdd(&tbuf[((size_t)b * 8 + r) * 2 + 1], cim);
        }
      }
  } else if (n0 < 20992) {                           // ---- B: Bz = Bt @ (ut*dt)
    const bool isBr = n0 < 12800;
    float* dst = isBr ? Bzr : Bzi;
#pragma unroll
    for (int mt = 0; mt < 4; ++mt)
#pragma unroll
      for (int j = 0; j < 4; ++j) {
        int b = m0 + wm + mt * 16 + quad * 4 + j;
        float dtb = dt[b];
#pragma unroll
        for (int g = 0; g < 2; ++g) {
          float s = 0.f;
#pragma unroll
          for (int h = 0; h < 2; ++h) {
            int nt = g * 2 + h;
            int n = ncol + nt * 16 + fr;
            int base = (n - 4608) & 8191;
            float v = acc[mt][nt][j] + bias[n];
            s += v * ut[(size_t)b * 32 + (base & 31)];
          }
          s *= dtb;
          s += __shfl_xor(s, 1); s += __shfl_xor(s, 2);
          s += __shfl_xor(s, 4); s += __shfl_xor(s, 8);
          if ((l & 15) == 0) {
            int d = (((ncol + g * 32) - 4608) & 8191) >> 5;
            dst[(size_t)b * 256 + d] = s;
          }
        }
      }
  } else {                                           // ---- D: yt init
#pragma unroll
    for (int mt = 0; mt < 4; ++mt)
#pragma unroll
      for (int j = 0; j < 4; ++j) {
        int b = m0 + wm + mt * 16 + quad * 4 + j;
        float dtb = dt[b];
#pragma unroll
        for (int g = 0; g < 2; ++g) {
          float s = 0.f;
#pragma unroll
          for (int h = 0; h < 2; ++h) {
            int nt = g * 2 + h;
            int n = ncol + nt * 16 + fr;
            int base = n - 20992;
            float v = acc[mt][nt][j] + bias[n];
            s += v * ut[(size_t)b * 32 + (base & 31)];
          }
          s *= dtb;
          s += __shfl_xor(s, 1); s += __shfl_xor(s, 2);
          s += __shfl_xor(s, 4); s += __shfl_xor(s, 8);
          int nn = ((ncol + g * 32) - 20992) >> 5;
          if ((l & 15) == 0 && nn < 50) ytout[(size_t)b * 50 + nn] = s;
        }
      }
  }
}

// ---------------------------------------------------------------- phase B GEMM (U)
__global__ __launch_bounds__(256, 3) void k_gemmB(
    const bf16* __restrict__ hz, const bf16* __restrict__ WT, const float* __restrict__ bias,
    const float* __restrict__ tbuf, float* __restrict__ lr) {
  int m0, n0;
  if (!tile_map(32, m0, n0)) return;
  f32x4 acc[4][4];
  gemm_direct(hz, WT, m0, n0, acc);
  const int l = threadIdx.x & 63, w = threadIdx.x >> 6;
  const int wm = (w >> 1) << 6, wn = (w & 1) << 6;
  const int fr = l & 15, quad = l >> 4;
  const int ncol = n0 + wn;
  const bool isUr = n0 < 2048;
#pragma unroll
  for (int mt = 0; mt < 4; ++mt)
#pragma unroll
    for (int j = 0; j < 4; ++j) {
      int b = m0 + wm + mt * 16 + quad * 4 + j;
#pragma unroll
      for (int nt = 0; nt < 4; ++nt) {
        int n = ncol + nt * 16 + fr;
        int base = n & 2047;
        int r = base & 7, d = base >> 3;
        float v = acc[mt][nt][j] + bias[n];
        float tre = tbuf[((size_t)b * 8 + r) * 2], tim = tbuf[((size_t)b * 8 + r) * 2 + 1];
        float cre = isUr ? v * tre : -v * tim;
        float cim = isUr ? v * tim :  v * tre;
        cre += __shfl_xor(cre, 1); cre += __shfl_xor(cre, 2); cre += __shfl_xor(cre, 4);
        cim += __shfl_xor(cim, 1); cim += __shfl_xor(cim, 2); cim += __shfl_xor(cim, 4);
        if ((l & 7) == 0) {
          atomicAdd(&lr[((size_t)b * 256 + d) * 2 + 0], cre);
          atomicAdd(&lr[((size_t)b * 256 + d) * 2 + 1], cim);
        }
      }
    }
}

// ---------------------------------------------------------------- z_next assembly
__global__ void k_assembleZ(const float* __restrict__ zt, const float* __restrict__ pa,
                            const float* __restrict__ po, const float* __restrict__ Bzr,
                            const float* __restrict__ Bzi, const float* __restrict__ lr,
                            float* __restrict__ zout, float* __restrict__ znr,
                            float* __restrict__ zni) {
  int i = blockIdx.x * 256 + threadIdx.x;      // 2048*256
  int b = i >> 8, d = i & 255;
  float a = pa[i], o = po[i];
  float sp = fmaxf(a, 0.f) + log1pf(expf(-fabsf(a)));   // softplus, stable
  float mag = expf(-sp);
  float Lr = mag * cosf(o), Li = mag * sinf(o);
  float zr = zt[(size_t)b * 512 + d], zi = zt[(size_t)b * 512 + 256 + d];
  float re = fmaf(Lr, zr, -Li * zi) + Bzr[i] + lr[2 * i];
  float im = fmaf(Lr, zi,  Li * zr) + Bzi[i] + lr[2 * i + 1];
  zout[(size_t)b * 512 + d] = re;
  zout[(size_t)b * 512 + 256 + d] = im;
  znr[i] = re; zni[i] = im;
}

// ---------------------------------------------------------------- phase C GEMM (C)
__global__ __launch_bounds__(256, 3) void k_gemmC(
    const bf16* __restrict__ hz, const bf16* __restrict__ WT, const float* __restrict__ bias,
    const float* __restrict__ znr, const float* __restrict__ zni, float* __restrict__ ytout) {
  int m0, n0;
  if (!tile_map(200, m0, n0)) return;
  f32x4 acc[4][4];
  gemm_direct(hz, WT, m0, n0, acc);
  const int l = threadIdx.x & 63, w = threadIdx.x >> 6;
  const int wm = (w >> 1) << 6, wn = (w & 1) << 6;
  const int fr = l & 15, quad = l >> 4;
  const int ncol = n0 + wn;
  const bool isCr = n0 < 12800;
  const int nb = ncol - (isCr ? 0 : 12800);
  const int nn = nb >> 8;
#pragma unroll
  for (int mt = 0; mt < 4; ++mt)
#pragma unroll
    for (int j = 0; j < 4; ++j) {
      int b = m0 + wm + mt * 16 + quad * 4 + j;
      float s = 0.f;
#pragma unroll
      for (int nt = 0; nt < 4; ++nt) {
        int n = ncol + nt * 16 + fr;
        int d = (nb + nt * 16 + fr) & 255;
        float v = acc[mt][nt][j] + bias[n];
        s += isCr ? v * znr[(size_t)b * 256 + d] : -(v * zni[(size_t)b * 256 + d]);
      }
      s += __shfl_xor(s, 1); s += __shfl_xor(s, 2);
      s += __shfl_xor(s, 4); s += __shfl_xor(s, 8);
      if ((l & 15) == 0) atomicAdd(&ytout[(size_t)b * 50 + nn], s);
    }
}

// ---------------------------------------------------------------- launch
extern "C" void kernel_launch(void* const* d_in, const int* in_sizes, int n_in,
                              void* d_out, int out_size, void* d_ws, size_t ws_size,
                              hipStream_t stream) {
  (void)in_sizes; (void)n_in; (void)out_size; (void)ws_size;
  const float* zt  = (const float*)d_in[0];
  const float* dt  = (const float*)d_in[1];
  const float* ut  = (const float*)d_in[2];
  const float* W0  = (const float*)d_in[3];  const float* b0  = (const float*)d_in[4];
  const float* W1  = (const float*)d_in[5];  const float* b1  = (const float*)d_in[6];
  const float* W2  = (const float*)d_in[7];  const float* b2  = (const float*)d_in[8];
  const float* Wa  = (const float*)d_in[9];  const float* ba  = (const float*)d_in[10];
  const float* Wo  = (const float*)d_in[11]; const float* bo  = (const float*)d_in[12];
  const float* WUr = (const float*)d_in[13]; const float* bUr = (const float*)d_in[14];
  const float* WUi = (const float*)d_in[15]; const float* bUi = (const float*)d_in[16];
  const float* WVr = (const float*)d_in[17]; const float* bVr = (const float*)d_in[18];
  const float* WVi = (const float*)d_in[19]; const float* bVi = (const float*)d_in[20];
  const float* WBr = (const float*)d_in[21]; const float* bBr = (const float*)d_in[22];
  const float* WBi = (const float*)d_in[23]; const float* bBi = (const float*)d_in[24];
  const float* WCr = (const float*)d_in[25]; const float* bCr = (const float*)d_in[26];
  const float* WCi = (const float*)d_in[27]; const float* bCi = (const float*)d_in[28];
  const float* WD  = (const float*)d_in[29]; const float* bD  = (const float*)d_in[30];
  const float* g0  = (const float*)d_in[31]; const float* be0 = (const float*)d_in[32];
  const float* g1  = (const float*)d_in[33]; const float* be1 = (const float*)d_in[34];

  char* ws = (char*)d_ws;
  bf16*  WTbig = (bf16*)(ws + 0);            // [22656, 512] bf16
  bf16*  WTU   = (bf16*)(ws + 23199744);     // [4096, 512]
  bf16*  WTC   = (bf16*)(ws + 27394048);     // [25600, 512]
  bf16*  hz    = (bf16*)(ws + 53608448);     // [2048, 512]
  float* s0    = (float*)(ws + 55705600);    // [2048, 128]
  float* s1    = (float*)(ws + 56754176);    // [2048, 128]
  float* mu0   = (float*)(ws + 57802752);
  float* rstd0 = mu0 + 128;
  float* mu1   = mu0 + 256;
  float* rstd1 = mu0 + 384;
  float* bbigA = (float*)(ws + 57804800);    // [22656]
  float* bbigB = (float*)(ws + 57895424);    // [4096]
  float* bbigC = (float*)(ws + 57911808);    // [25600]
  float* pa    = (float*)(ws + 58014208);    // [2048, 256]
  float* po    = (float*)(ws + 60111360);
  float* Bzr   = (float*)(ws + 62208512);
  float* Bzi   = (float*)(ws + 64305664);
  float* tbuf  = (float*)(ws + 66402816);    // [2048, 8, 2]
  float* lr    = (float*)(ws + 66533888);    // [2048, 256, 2]
  float* znr   = (float*)(ws + 70728192);
  float* zni   = (float*)(ws + 72825344);    // ends 74,922,496
  float* zout  = (float*)d_out;
  float* ytout = zout + 2048 * 512;

  k_prep<<<205, 256, 0, stream>>>(ba, bo, bVr, bVi, bBr, bBi, bD, bUr, bUi, bCr, bCi,
                                  bbigA, bbigB, bbigC);

  TArgs ta; int tile0 = 0; int idx = 0;
  auto add = [&](const float* src, bf16* dst, int N) {
    int ntn = N >> 6;
    ta.e[idx].src = src; ta.e[idx].dst = dst; ta.e[idx].N = N;
    ta.e[idx].tile0 = tile0; ta.e[idx].ntn = ntn;
    tile0 += ntn * 8; ++idx;
  };
  add(Wa,  WTbig + (size_t)0 * 512,     256);
  add(Wo,  WTbig + (size_t)256 * 512,   256);
  add(WVr, WTbig + (size_t)512 * 512,   2048);
  add(WVi, WTbig + (size_t)2560 * 512,  2048);
  add(WBr, WTbig + (size_t)4608 * 512,  8192);
  add(WBi, WTbig + (size_t)12800 * 512, 8192);
  add(WD,  WTbig + (size_t)20992 * 512, 1600);
  add(WUr, WTU,                         2048);
  add(WUi, WTU + (size_t)2048 * 512,    2048);
  add(WCr, WTC,                         12800);
  add(WCi, WTC + (size_t)12800 * 512,   12800);
  k_transpose<<<tile0, 256, 0, stream>>>(ta);

  hipMemsetAsync(tbuf, 0, 131072, stream);
  hipMemsetAsync(lr, 0, 4194304, stream);

  k_lin0<<<1024, 256, 0, stream>>>(zt, dt, ut, W0, b0, s0);
  k_stats<<<128, 256, 0, stream>>>(s0, mu0, rstd0);
  k_lin1<<<1024, 256, 0, stream>>>(s0, mu0, rstd0, g0, be0, W1, b1, s1);
  k_stats<<<128, 256, 0, stream>>>(s1, mu1, rstd1);
  k_lin2<<<4096, 256, 0, stream>>>(s1, mu1, rstd1, g1, be1, W2, b2, hz);

  // NT=177 -> pad to 184 n-tiles; invalid tiles early-exit.
  k_gemmA<<<184 * 16, 256, 0, stream>>>(hz, WTbig, bbigA, zt, dt, ut,
                                        pa, po, Bzr, Bzi, tbuf, ytout);
  k_gemmB<<<32 * 16, 256, 0, stream>>>(hz, WTU, bbigB, tbuf, lr);
  k_assembleZ<<<2048, 256, 0, stream>>>(zt, pa, po, Bzr, Bzi, lr, zout, znr, zni);
  k_gemmC<<<200 * 16, 256, 0, stream>>>(hz, WTC, bbigC, znr, zni, ytout);
}

// Round 5
// 646.785 us; speedup vs baseline: 1.4008x; 1.4008x over previous
//
#include <hip/hip_runtime.h>
#include <hip/hip_bf16.h>
#include <cstdint>
#include <cstddef>

// S4D-PLR transition model, MI355X (gfx950).
// R4: R3's zero-barrier wave-private staging GEMM + the WAR-race fix:
// explicit s_waitcnt lgkmcnt(0) after fragment ds_reads, BEFORE the next
// iteration's DMA can be issued. (R3 failed nondeterministically because the
// compiler may sink MFMAs/lgkm-waits past the next global_load_lds issue,
// letting the DMA overwrite LDS words whose ds_read was still in flight.)

typedef __bf16 bf16;
typedef __bf16 bf16x8 __attribute__((ext_vector_type(8)));
typedef __bf16 bf16x4 __attribute__((ext_vector_type(4)));
typedef float f32x4 __attribute__((ext_vector_type(4)));

// ---------------------------------------------------------------- async copy
__device__ __forceinline__ void async16(const void* g, void* l) {
  __builtin_amdgcn_global_load_lds((const __attribute__((address_space(1))) void*)g,
                                   (__attribute__((address_space(3))) void*)l, 16, 0, 0);
}

// ---------------------------------------------------------------- tile map
// XCD-aware: blocks L%8 -> XCD; consecutive s=L/8 on one XCD sweep all 16
// m-tiles of one n-tile (B-tile stays in that XCD's L2).
__device__ __forceinline__ bool tile_map(int NT, int& m0, int& n0) {
  int L = blockIdx.x;
  int x = L & 7, s = L >> 3;
  int nt = ((s >> 4) << 3) + x;
  if (nt >= NT) return false;
  n0 = nt << 7;
  m0 = (s & 15) << 7;
  return true;
}

// ---------------------------------------------------------------- GEMM core
// C[128x128] = A[128x512] * Bw^T (Bw [N,512] bf16, k-contiguous).
// 4 waves (2x2), each 64x64 via 4x4 mfma_f32_16x16x32_bf16.
// Wave-private staging: lds[w*8192 .. +8191] elems; buf p at +p*4096;
// A rows at [r*32 + kc*8], B at +2048. Slot (r,kc) holds source k-chunk
// kc ^ ((r>>1)&3) (bank swizzle, applied on the global-address side).
// Ordering per iter (all pinned by memory-clobber asm):
//   issue(next buf) -> vmcnt(8) [cur buf landed] -> ds_read cur buf
//   -> lgkmcnt(0) [reads COMPLETE] -> MFMA.
// The lgkm drain guarantees no ds_read is outstanding when the following
// iteration's DMA (which overwrites this buffer one iter later) is issued.
__device__ __forceinline__ void gemm_wp(const bf16* __restrict__ A,
                                        const bf16* __restrict__ Bw,
                                        int m0, int n0,
                                        bf16* lds, f32x4 acc[4][4]) {
  const int tid = threadIdx.x;
  const int w = tid >> 6, l = tid & 63;
  const int wm = (w >> 1) << 6, wn = (w & 1) << 6;
  const int fr = l & 15, q = l >> 4;
  const int lr = l >> 2;                                 // row-within-DMA-instr
  const int koff = ((l & 3) ^ ((l >> 3) & 3)) << 3;      // swizzled k-chunk
  const bf16* ag = A + (size_t)(m0 + wm + lr) * 512 + koff;
  const bf16* bg = Bw + (size_t)(n0 + wn + lr) * 512 + koff;
  bf16* lw = lds + (w << 13);                            // 8192 elems/wave
  const int sw = (q ^ ((fr >> 1) & 3)) << 3;             // reader un-swizzle

#pragma unroll
  for (int mt = 0; mt < 4; ++mt)
#pragma unroll
    for (int nt = 0; nt < 4; ++nt) { f32x4 z = {0.f, 0.f, 0.f, 0.f}; acc[mt][nt] = z; }

  auto issue = [&](int kt, int p) {
    bf16* d = lw + (p << 12);
#pragma unroll
    for (int i = 0; i < 4; ++i) async16(ag + kt + i * 8192, d + (i << 9));
#pragma unroll
    for (int i = 0; i < 4; ++i) async16(bg + kt + i * 8192, d + 2048 + (i << 9));
  };

  issue(0, 0);
#pragma unroll
  for (int it = 0; it < 16; ++it) {
    const int p = it & 1;
    if (it < 15) {
      issue((it + 1) << 5, p ^ 1);
      asm volatile("s_waitcnt vmcnt(8)" ::: "memory");   // own cur-step DMAs done
    } else {
      asm volatile("s_waitcnt vmcnt(0)" ::: "memory");
    }
    const bf16* ab = lw + (p << 12);
    const bf16* bb = ab + 2048;
    bf16x8 af[4], bfv[4];
#pragma unroll
    for (int mt = 0; mt < 4; ++mt)
      af[mt] = *(const bf16x8*)(ab + (mt * 16 + fr) * 32 + sw);
#pragma unroll
    for (int nt = 0; nt < 4; ++nt)
      bfv[nt] = *(const bf16x8*)(bb + (nt * 16 + fr) * 32 + sw);
    asm volatile("s_waitcnt lgkmcnt(0)" ::: "memory");   // WAR fix: reads done
#pragma unroll
    for (int mt = 0; mt < 4; ++mt)
#pragma unroll
      for (int nt = 0; nt < 4; ++nt)
        acc[mt][nt] = __builtin_amdgcn_mfma_f32_16x16x32_bf16(af[mt], bfv[nt],
                                                              acc[mt][nt], 0, 0, 0);
  }
}
// C/D layout (verified m89/m91): col = lane&15, row = (lane>>4)*4 + reg.

// ---------------------------------------------------------------- weight transpose
// All segments: K = 512, N multiple of 64 -> no guards needed.
struct TEntry { const float* src; bf16* dst; int N, tile0, ntn; };
struct TArgs { TEntry e[11]; };

__global__ void k_transpose(TArgs a) {
  __shared__ float tile[64][65];
  int t = blockIdx.x;
  int ei = 0;
  while (ei < 10 && t >= a.e[ei + 1].tile0) ++ei;
  const TEntry E = a.e[ei];
  int lt = t - E.tile0;
  int tk = lt / E.ntn, tn = lt - tk * E.ntn;
  int k0 = tk << 6, n0 = tn << 6;
  int tid = threadIdx.x;
#pragma unroll
  for (int i = 0; i < 4; ++i) {
    int idx = tid + i * 256;                // 1024 float4 chunks
    int kk = idx >> 4, c4 = (idx & 15) << 2;
    const float4 v = *(const float4*)(E.src + (size_t)(k0 + kk) * E.N + n0 + c4);
    tile[c4 + 0][kk] = v.x; tile[c4 + 1][kk] = v.y;
    tile[c4 + 2][kk] = v.z; tile[c4 + 3][kk] = v.w;
  }
  __syncthreads();
#pragma unroll
  for (int i = 0; i < 4; ++i) {
    int idx = tid + i * 256;
    int nn = idx >> 4, k4 = (idx & 15) << 2;
    bf16x4 o;
    o[0] = (bf16)tile[nn][k4 + 0]; o[1] = (bf16)tile[nn][k4 + 1];
    o[2] = (bf16)tile[nn][k4 + 2]; o[3] = (bf16)tile[nn][k4 + 3];
    *(bf16x4*)(E.dst + (size_t)(n0 + nn) * 512 + k0 + k4) = o;
  }
}

// ---------------------------------------------------------------- bias gather
__global__ void k_prep(const float* ba, const float* bo, const float* bVr, const float* bVi,
                       const float* bBr, const float* bBi, const float* bD,
                       const float* bUr, const float* bUi, const float* bCr, const float* bCi,
                       float* bbigA, float* bbigB, float* bbigC) {
  int i = blockIdx.x * 256 + threadIdx.x;
  if (i < 22656) {
    float v;
    if (i < 256) v = ba[i];
    else if (i < 512) v = bo[i - 256];
    else if (i < 2560) v = bVr[i - 512];
    else if (i < 4608) v = bVi[i - 2560];
    else if (i < 12800) v = bBr[i - 4608];
    else if (i < 20992) v = bBi[i - 12800];
    else if (i < 22592) v = bD[i - 20992];
    else v = 0.f;
    bbigA[i] = v;
  }
  int j = i - 22656;
  if (j >= 0 && j < 4096) bbigB[j] = (j < 2048) ? bUr[j] : bUi[j - 2048];
  int m = i - (22656 + 4096);
  if (m >= 0 && m < 25600) bbigC[m] = (m < 12800) ? bCr[m] : bCi[m - 12800];
}

// ---------------------------------------------------------------- selector MLP (fp32)
__global__ void k_lin0(const float* __restrict__ zt, const float* __restrict__ dt,
                       const float* __restrict__ ut, const float* __restrict__ W0,
                       const float* __restrict__ b0, float* __restrict__ s0) {
  int i = blockIdx.x * 256 + threadIdx.x;      // 2048*128
  int b = i >> 7, c = i & 127;
  const float* w = W0 + c;
  const float* x = zt + (size_t)b * 512;
  float acc = b0[c];
#pragma unroll 4
  for (int k = 0; k < 512; ++k) acc = fmaf(x[k], w[(size_t)k * 128], acc);
  const float* u = ut + (size_t)b * 32;
#pragma unroll
  for (int k = 0; k < 32; ++k) acc = fmaf(u[k], w[(size_t)(512 + k) * 128], acc);
  acc = fmaf(dt[b], w[(size_t)544 * 128], acc);
  s0[i] = acc;
}

__global__ void k_stats(const float* __restrict__ s, float* __restrict__ mu,
                        float* __restrict__ rstd) {
  int c = blockIdx.x;                           // 128 columns
  float sm = 0.f, sq = 0.f;
  for (int r = threadIdx.x; r < 2048; r += 256) {
    float v = s[(size_t)r * 128 + c];
    sm += v; sq += v * v;
  }
#pragma unroll
  for (int o = 32; o >= 1; o >>= 1) { sm += __shfl_down(sm, o); sq += __shfl_down(sq, o); }
  __shared__ float red[8];
  int w = threadIdx.x >> 6;
  if ((threadIdx.x & 63) == 0) { red[w] = sm; red[4 + w] = sq; }
  __syncthreads();
  if (threadIdx.x == 0) {
    float S = red[0] + red[1] + red[2] + red[3];
    float Q = red[4] + red[5] + red[6] + red[7];
    float m = S * (1.f / 2048.f);
    float var = Q * (1.f / 2048.f) - m * m;    // biased var (training-mode BN)
    mu[c] = m;
    rstd[c] = rsqrtf(var + 1e-5f);
  }
}

__global__ void k_lin1(const float* __restrict__ s0, const float* __restrict__ mu,
                       const float* __restrict__ rstd, const float* __restrict__ g,
                       const float* __restrict__ be, const float* __restrict__ W1,
                       const float* __restrict__ b1, float* __restrict__ s1) {
  int i = blockIdx.x * 256 + threadIdx.x;      // 2048*128
  int b = i >> 7, c = i & 127;
  const float* w = W1 + c;
  const float* x = s0 + (size_t)b * 128;
  float acc = b1[c];
#pragma unroll 4
  for (int k = 0; k < 128; ++k) {
    float h = fmaxf(fmaf((x[k] - mu[k]) * rstd[k], g[k], be[k]), 0.f);
    acc = fmaf(h, w[(size_t)k * 128], acc);
  }
  s1[i] = acc;
}

__global__ void k_lin2(const float* __restrict__ s1, const float* __restrict__ mu,
                       const float* __restrict__ rstd, const float* __restrict__ g,
                       const float* __restrict__ be, const float* __restrict__ W2,
                       const float* __restrict__ b2, bf16* __restrict__ hz) {
  int i = blockIdx.x * 256 + threadIdx.x;      // 2048*512
  int b = i >> 9, c = i & 511;
  const float* w = W2 + c;
  const float* x = s1 + (size_t)b * 128;
  float acc = b2[c];
#pragma unroll 4
  for (int k = 0; k < 128; ++k) {
    float h = fmaxf(fmaf((x[k] - mu[k]) * rstd[k], g[k], be[k]), 0.f);
    acc = fmaf(h, w[(size_t)k * 512], acc);
  }
  hz[i] = (bf16)acc;
}

// ---------------------------------------------------------------- phase A GEMM
// columns: [0,256) a | [256,512) o | [512,2560) Vr | [2560,4608) Vi
//          [4608,12800) Br | [12800,20992) Bi | [20992,22592) D | pad to 22656
__global__ __launch_bounds__(256) void k_gemmA(
    const bf16* __restrict__ hz, const bf16* __restrict__ WT, const float* __restrict__ bias,
    const float* __restrict__ zt, const float* __restrict__ dt, const float* __restrict__ ut,
    float* __restrict__ pa, float* __restrict__ po,
    float* __restrict__ Bzr, float* __restrict__ Bzi,
    float* __restrict__ tbuf, float* __restrict__ ytout) {
  int m0, n0;
  if (!tile_map(177, m0, n0)) return;
  __shared__ __align__(16) bf16 lds[32768];
  f32x4 acc[4][4];
  gemm_wp(hz, WT, m0, n0, lds, acc);
  const int l = threadIdx.x & 63, w = threadIdx.x >> 6;
  const int wm = (w >> 1) << 6, wn = (w & 1) << 6;
  const int fr = l & 15, quad = l >> 4;
  const int ncol = n0 + wn;

  if (n0 < 512) {                                    // ---- a / o pre-acts
    float* dst = (n0 < 256) ? pa : po;
    int cb = ncol - ((n0 < 256) ? 0 : 256);
#pragma unroll
    for (int mt = 0; mt < 4; ++mt)
#pragma unroll
      for (int j = 0; j < 4; ++j) {
        int b = m0 + wm + mt * 16 + quad * 4 + j;
#pragma unroll
        for (int nt = 0; nt < 4; ++nt) {
          int n = ncol + nt * 16 + fr;
          dst[(size_t)b * 256 + (cb + nt * 16 + fr)] = acc[mt][nt][j] + bias[n];
        }
      }
  } else if (n0 < 4608) {                            // ---- V: t = conj(V)^T z
    const bool isVr = n0 < 2560;
#pragma unroll
    for (int mt = 0; mt < 4; ++mt)
#pragma unroll
      for (int j = 0; j < 4; ++j) {
        int b = m0 + wm + mt * 16 + quad * 4 + j;
        float cre = 0.f, cim = 0.f;
#pragma unroll
        for (int nt = 0; nt < 4; ++nt) {
          int n = ncol + nt * 16 + fr;
          float v = acc[mt][nt][j] + bias[n];
          int d = ((n - 512) & 2047) >> 3;
          float zr = zt[(size_t)b * 512 + d], zi = zt[(size_t)b * 512 + 256 + d];
          if (isVr) { cre += v * zr; cim += v * zi; }
          else      { cre += v * zi; cim -= v * zr; }
        }
        cre += __shfl_xor(cre, 8);
        cim += __shfl_xor(cim, 8);
        if ((l & 8) == 0) {
          int r = fr & 7;
          atomicAdd(&tbuf[((size_t)b * 8 + r) * 2 + 0], cre);
          atomicAdd(&tbuf[((size_t)b * 8 + r) * 2 + 1], cim);
        }
      }
  } else if (n0 < 20992) {                           // ---- B: Bz = Bt @ (ut*dt)
    const bool isBr = n0 < 12800;
    float* dst = isBr ? Bzr : Bzi;
#pragma unroll
    for (int mt = 0; mt < 4; ++mt)
#pragma unroll
      for (int j = 0; j < 4; ++j) {
        int b = m0 + wm + mt * 16 + quad * 4 + j;
        float dtb = dt[b];
#pragma unroll
        for (int g = 0; g < 2; ++g) {
          float s = 0.f;
#pragma unroll
          for (int h = 0; h < 2; ++h) {
            int nt = g * 2 + h;
            int n = ncol + nt * 16 + fr;
            int base = (n - 4608) & 8191;
            float v = acc[mt][nt][j] + bias[n];
            s += v * ut[(size_t)b * 32 + (base & 31)];
          }
          s *= dtb;
          s += __shfl_xor(s, 1); s += __shfl_xor(s, 2);
          s += __shfl_xor(s, 4); s += __shfl_xor(s, 8);
          if ((l & 15) == 0) {
            int d = (((ncol + g * 32) - 4608) & 8191) >> 5;
            dst[(size_t)b * 256 + d] = s;
          }
        }
      }
  } else {                                           // ---- D: yt init
#pragma unroll
    for (int mt = 0; mt < 4; ++mt)
#pragma unroll
      for (int j = 0; j < 4; ++j) {
        int b = m0 + wm + mt * 16 + quad * 4 + j;
        float dtb = dt[b];
#pragma unroll
        for (int g = 0; g < 2; ++g) {
          float s = 0.f;
#pragma unroll
          for (int h = 0; h < 2; ++h) {
            int nt = g * 2 + h;
            int n = ncol + nt * 16 + fr;
            int base = n - 20992;
            float v = acc[mt][nt][j] + bias[n];
            s += v * ut[(size_t)b * 32 + (base & 31)];
          }
          s *= dtb;
          s += __shfl_xor(s, 1); s += __shfl_xor(s, 2);
          s += __shfl_xor(s, 4); s += __shfl_xor(s, 8);
          int nn = ((ncol + g * 32) - 20992) >> 5;
          if ((l & 15) == 0 && nn < 50) ytout[(size_t)b * 50 + nn] = s;
        }
      }
  }
}

// ---------------------------------------------------------------- phase B GEMM (U)
__global__ __launch_bounds__(256) void k_gemmB(
    const bf16* __restrict__ hz, const bf16* __restrict__ WT, const float* __restrict__ bias,
    const float* __restrict__ tbuf, float* __restrict__ lr) {
  int m0, n0;
  if (!tile_map(32, m0, n0)) return;
  __shared__ __align__(16) bf16 lds[32768];
  f32x4 acc[4][4];
  gemm_wp(hz, WT, m0, n0, lds, acc);
  const int l = threadIdx.x & 63, w = threadIdx.x >> 6;
  const int wm = (w >> 1) << 6, wn = (w & 1) << 6;
  const int fr = l & 15, quad = l >> 4;
  const int ncol = n0 + wn;
  const bool isUr = n0 < 2048;
#pragma unroll
  for (int mt = 0; mt < 4; ++mt)
#pragma unroll
    for (int j = 0; j < 4; ++j) {
      int b = m0 + wm + mt * 16 + quad * 4 + j;
#pragma unroll
      for (int nt = 0; nt < 4; ++nt) {
        int n = ncol + nt * 16 + fr;
        int base = n & 2047;
        int r = base & 7, d = base >> 3;
        float v = acc[mt][nt][j] + bias[n];
        float tre = tbuf[((size_t)b * 8 + r) * 2], tim = tbuf[((size_t)b * 8 + r) * 2 + 1];
        float cre = isUr ? v * tre : -v * tim;
        float cim = isUr ? v * tim :  v * tre;
        cre += __shfl_xor(cre, 1); cre += __shfl_xor(cre, 2); cre += __shfl_xor(cre, 4);
        cim += __shfl_xor(cim, 1); cim += __shfl_xor(cim, 2); cim += __shfl_xor(cim, 4);
        if ((l & 7) == 0) {
          atomicAdd(&lr[((size_t)b * 256 + d) * 2 + 0], cre);
          atomicAdd(&lr[((size_t)b * 256 + d) * 2 + 1], cim);
        }
      }
    }
}

// ---------------------------------------------------------------- z_next assembly
__global__ void k_assembleZ(const float* __restrict__ zt, const float* __restrict__ pa,
                            const float* __restrict__ po, const float* __restrict__ Bzr,
                            const float* __restrict__ Bzi, const float* __restrict__ lr,
                            float* __restrict__ zout, float* __restrict__ znr,
                            float* __restrict__ zni) {
  int i = blockIdx.x * 256 + threadIdx.x;      // 2048*256
  int b = i >> 8, d = i & 255;
  float a = pa[i], o = po[i];
  float sp = fmaxf(a, 0.f) + log1pf(expf(-fabsf(a)));   // softplus, stable
  float mag = expf(-sp);
  float Lr = mag * cosf(o), Li = mag * sinf(o);
  float zr = zt[(size_t)b * 512 + d], zi = zt[(size_t)b * 512 + 256 + d];
  float re = fmaf(Lr, zr, -Li * zi) + Bzr[i] + lr[2 * i];
  float im = fmaf(Lr, zi,  Li * zr) + Bzi[i] + lr[2 * i + 1];
  zout[(size_t)b * 512 + d] = re;
  zout[(size_t)b * 512 + 256 + d] = im;
  znr[i] = re; zni[i] = im;
}

// ---------------------------------------------------------------- phase C GEMM (C)
__global__ __launch_bounds__(256) void k_gemmC(
    const bf16* __restrict__ hz, const bf16* __restrict__ WT, const float* __restrict__ bias,
    const float* __restrict__ znr, const float* __restrict__ zni, float* __restrict__ ytout) {
  int m0, n0;
  if (!tile_map(200, m0, n0)) return;
  __shared__ __align__(16) bf16 lds[32768];
  f32x4 acc[4][4];
  gemm_wp(hz, WT, m0, n0, lds, acc);
  const int l = threadIdx.x & 63, w = threadIdx.x >> 6;
  const int wm = (w >> 1) << 6, wn = (w & 1) << 6;
  const int fr = l & 15, quad = l >> 4;
  const int ncol = n0 + wn;
  const bool isCr = n0 < 12800;
  const int nb = ncol - (isCr ? 0 : 12800);
  const int nn = nb >> 8;
#pragma unroll
  for (int mt = 0; mt < 4; ++mt)
#pragma unroll
    for (int j = 0; j < 4; ++j) {
      int b = m0 + wm + mt * 16 + quad * 4 + j;
      float s = 0.f;
#pragma unroll
      for (int nt = 0; nt < 4; ++nt) {
        int n = ncol + nt * 16 + fr;
        int d = (nb + nt * 16 + fr) & 255;
        float v = acc[mt][nt][j] + bias[n];
        s += isCr ? v * znr[(size_t)b * 256 + d] : -(v * zni[(size_t)b * 256 + d]);
      }
      s += __shfl_xor(s, 1); s += __shfl_xor(s, 2);
      s += __shfl_xor(s, 4); s += __shfl_xor(s, 8);
      if ((l & 15) == 0) atomicAdd(&ytout[(size_t)b * 50 + nn], s);
    }
}

// ---------------------------------------------------------------- launch
extern "C" void kernel_launch(void* const* d_in, const int* in_sizes, int n_in,
                              void* d_out, int out_size, void* d_ws, size_t ws_size,
                              hipStream_t stream) {
  (void)in_sizes; (void)n_in; (void)out_size; (void)ws_size;
  const float* zt  = (const float*)d_in[0];
  const float* dt  = (const float*)d_in[1];
  const float* ut  = (const float*)d_in[2];
  const float* W0  = (const float*)d_in[3];  const float* b0  = (const float*)d_in[4];
  const float* W1  = (const float*)d_in[5];  const float* b1  = (const float*)d_in[6];
  const float* W2  = (const float*)d_in[7];  const float* b2  = (const float*)d_in[8];
  const float* Wa  = (const float*)d_in[9];  const float* ba  = (const float*)d_in[10];
  const float* Wo  = (const float*)d_in[11]; const float* bo  = (const float*)d_in[12];
  const float* WUr = (const float*)d_in[13]; const float* bUr = (const float*)d_in[14];
  const float* WUi = (const float*)d_in[15]; const float* bUi = (const float*)d_in[16];
  const float* WVr = (const float*)d_in[17]; const float* bVr = (const float*)d_in[18];
  const float* WVi = (const float*)d_in[19]; const float* bVi = (const float*)d_in[20];
  const float* WBr = (const float*)d_in[21]; const float* bBr = (const float*)d_in[22];
  const float* WBi = (const float*)d_in[23]; const float* bBi = (const float*)d_in[24];
  const float* WCr = (const float*)d_in[25]; const float* bCr = (const float*)d_in[26];
  const float* WCi = (const float*)d_in[27]; const float* bCi = (const float*)d_in[28];
  const float* WD  = (const float*)d_in[29]; const float* bD  = (const float*)d_in[30];
  const float* g0  = (const float*)d_in[31]; const float* be0 = (const float*)d_in[32];
  const float* g1  = (const float*)d_in[33]; const float* be1 = (const float*)d_in[34];

  char* ws = (char*)d_ws;
  bf16*  WTbig = (bf16*)(ws + 0);            // [22656, 512] bf16
  bf16*  WTU   = (bf16*)(ws + 23199744);     // [4096, 512]
  bf16*  WTC   = (bf16*)(ws + 27394048);     // [25600, 512]
  bf16*  hz    = (bf16*)(ws + 53608448);     // [2048, 512]
  float* s0    = (float*)(ws + 55705600);    // [2048, 128]
  float* s1    = (float*)(ws + 56754176);    // [2048, 128]
  float* mu0   = (float*)(ws + 57802752);
  float* rstd0 = mu0 + 128;
  float* mu1   = mu0 + 256;
  float* rstd1 = mu0 + 384;
  float* bbigA = (float*)(ws + 57804800);    // [22656]
  float* bbigB = (float*)(ws + 57895424);    // [4096]
  float* bbigC = (float*)(ws + 57911808);    // [25600]
  float* pa    = (float*)(ws + 58014208);    // [2048, 256]
  float* po    = (float*)(ws + 60111360);
  float* Bzr   = (float*)(ws + 62208512);
  float* Bzi   = (float*)(ws + 64305664);
  float* tbuf  = (float*)(ws + 66402816);    // [2048, 8, 2]
  float* lr    = (float*)(ws + 66533888);    // [2048, 256, 2]
  float* znr   = (float*)(ws + 70728192);
  float* zni   = (float*)(ws + 72825344);    // ends 74,922,496
  float* zout  = (float*)d_out;
  float* ytout = zout + 2048 * 512;

  k_prep<<<205, 256, 0, stream>>>(ba, bo, bVr, bVi, bBr, bBi, bD, bUr, bUi, bCr, bCi,
                                  bbigA, bbigB, bbigC);

  TArgs ta; int tile0 = 0; int idx = 0;
  auto add = [&](const float* src, bf16* dst, int N) {
    int ntn = N >> 6;
    ta.e[idx].src = src; ta.e[idx].dst = dst; ta.e[idx].N = N;
    ta.e[idx].tile0 = tile0; ta.e[idx].ntn = ntn;
    tile0 += ntn * 8; ++idx;
  };
  add(Wa,  WTbig + (size_t)0 * 512,     256);
  add(Wo,  WTbig + (size_t)256 * 512,   256);
  add(WVr, WTbig + (size_t)512 * 512,   2048);
  add(WVi, WTbig + (size_t)2560 * 512,  2048);
  add(WBr, WTbig + (size_t)4608 * 512,  8192);
  add(WBi, WTbig + (size_t)12800 * 512, 8192);
  add(WD,  WTbig + (size_t)20992 * 512, 1600);
  add(WUr, WTU,                         2048);
  add(WUi, WTU + (size_t)2048 * 512,    2048);
  add(WCr, WTC,                         12800);
  add(WCi, WTC + (size_t)12800 * 512,   12800);
  k_transpose<<<tile0, 256, 0, stream>>>(ta);

  hipMemsetAsync(tbuf, 0, 131072, stream);
  hipMemsetAsync(lr, 0, 4194304, stream);

  k_lin0<<<1024, 256, 0, stream>>>(zt, dt, ut, W0, b0, s0);
  k_stats<<<128, 256, 0, stream>>>(s0, mu0, rstd0);
  k_lin1<<<1024, 256, 0, stream>>>(s0, mu0, rstd0, g0, be0, W1, b1, s1);
  k_stats<<<128, 256, 0, stream>>>(s1, mu1, rstd1);
  k_lin2<<<4096, 256, 0, stream>>>(s1, mu1, rstd1, g1, be1, W2, b2, hz);

  // NT=177 -> pad to 184 n-tiles; invalid tiles early-exit (no barriers inside).
  k_gemmA<<<184 * 16, 256, 0, stream>>>(hz, WTbig, bbigA, zt, dt, ut,
                                        pa, po, Bzr, Bzi, tbuf, ytout);
  k_gemmB<<<32 * 16, 256, 0, stream>>>(hz, WTU, bbigB, tbuf, lr);
  k_assembleZ<<<2048, 256, 0, stream>>>(zt, pa, po, Bzr, Bzi, lr, zout, znr, zni);
  k_gemmC<<<200 * 16, 256, 0, stream>>>(hz, WTC, bbigC, znr, zni, ytout);
}

// Round 6
// 586.139 us; speedup vs baseline: 1.5458x; 1.1035x over previous
//
#include <hip/hip_runtime.h>
#include <hip/hip_bf16.h>
#include <cstdint>
#include <cstddef>

// S4D-PLR transition model, MI355X (gfx950).
// R5: block-shared LDS staging, 3 buffers (48KB), prefetch depth 2, ONE raw
// s_barrier per K-step, vmcnt(4) pacing (never drains to 0 mid-loop).
// Safety: reads of buf(it) are lgkm-drained before barrier(it+1); the only
// overwrite of buf(it) is issued after barrier(it+2). 3 blocks/CU.

typedef __bf16 bf16;
typedef __bf16 bf16x8 __attribute__((ext_vector_type(8)));
typedef __bf16 bf16x4 __attribute__((ext_vector_type(4)));
typedef float f32x4 __attribute__((ext_vector_type(4)));

// ---------------------------------------------------------------- async copy
__device__ __forceinline__ void async16(const void* g, void* l) {
  __builtin_amdgcn_global_load_lds((const __attribute__((address_space(1))) void*)g,
                                   (__attribute__((address_space(3))) void*)l, 16, 0, 0);
}

// ---------------------------------------------------------------- tile map
// XCD-aware: blocks L%8 -> XCD; consecutive s=L/8 on one XCD sweep all 16
// m-tiles of one n-tile (B-tile stays in that XCD's L2).
__device__ __forceinline__ bool tile_map(int NT, int& m0, int& n0) {
  int L = blockIdx.x;
  int x = L & 7, s = L >> 3;
  int nt = ((s >> 4) << 3) + x;
  if (nt >= NT) return false;
  n0 = nt << 7;
  m0 = (s & 15) << 7;
  return true;
}

// ---------------------------------------------------------------- GEMM core
// C[128x128] = A[128x512] * Bw^T (Bw [N,512] bf16, k-contiguous).
// 4 waves (2x2), each 64x64 via 4x4 mfma_f32_16x16x32_bf16.
// LDS: 3 buffers, buf p at lds+p*8192 elems; A-tile (128x32) at +0,
// B-tile at +4096. Chunk c (=tid, tid+256) holds row c>>2, swizzled k-chunk
// (c&3)^((row>>1)&3) (bank swizzle on the global-address side; R1-verified
// conflict-free). Per iter: vmcnt(4) [buf it landed] -> s_barrier ->
// ds_read buf it -> lgkmcnt(0) -> issue buf it+2 -> MFMA.
__device__ __forceinline__ void gemm_p3(const bf16* __restrict__ A,
                                        const bf16* __restrict__ Bw,
                                        int m0, int n0,
                                        bf16* lds, f32x4 acc[4][4]) {
  const int tid = threadIdx.x;
  const int w = tid >> 6, l = tid & 63;
  const int wm = (w >> 1) << 6, wn = (w & 1) << 6;
  const int fr = l & 15, q = l >> 4;

  // staging chunks: c0 = tid, c1 = tid + 256 (1024 chunks per K-step: 512 A + 512 B)
  const int c0 = tid, c1 = tid + 256;
  const int r0 = c0 >> 2, k0 = ((c0 & 3) ^ ((r0 >> 1) & 3)) << 3;
  const int r1 = c1 >> 2, k1 = ((c1 & 3) ^ ((r1 >> 1) & 3)) << 3;
  const bf16* a0 = A + (size_t)(m0 + r0) * 512 + k0;
  const bf16* a1 = A + (size_t)(m0 + r1) * 512 + k1;
  const bf16* b0 = Bw + (size_t)(n0 + r0) * 512 + k0;
  const bf16* b1 = Bw + (size_t)(n0 + r1) * 512 + k1;
  const int sw = (q ^ ((fr >> 1) & 3)) << 3;             // reader un-swizzle

#pragma unroll
  for (int mt = 0; mt < 4; ++mt)
#pragma unroll
    for (int nt = 0; nt < 4; ++nt) { f32x4 z = {0.f, 0.f, 0.f, 0.f}; acc[mt][nt] = z; }

  auto issue = [&](int kt, int p) {
    bf16* d = lds + p * 8192;
    async16(a0 + kt, d + (c0 << 3));
    async16(a1 + kt, d + (c1 << 3));
    async16(b0 + kt, d + 4096 + (c0 << 3));
    async16(b1 + kt, d + 4096 + (c1 << 3));
  };

  issue(0, 0);
  issue(32, 1);
#pragma unroll
  for (int it = 0; it < 16; ++it) {
    const int p = it % 3;
    if (it < 14) asm volatile("s_waitcnt vmcnt(4)" ::: "memory");  // buf it landed
    else         asm volatile("s_waitcnt vmcnt(0)" ::: "memory");
    asm volatile("s_barrier" ::: "memory");                         // all waves ready
    const bf16* ab = lds + p * 8192;
    const bf16* bb = ab + 4096;
    bf16x8 af[4], bfv[4];
#pragma unroll
    for (int mt = 0; mt < 4; ++mt)
      af[mt] = *(const bf16x8*)(ab + (wm + mt * 16 + fr) * 32 + sw);
#pragma unroll
    for (int nt = 0; nt < 4; ++nt)
      bfv[nt] = *(const bf16x8*)(bb + (wn + nt * 16 + fr) * 32 + sw);
    asm volatile("s_waitcnt lgkmcnt(0)" ::: "memory");   // reads COMPLETE (WAR)
    if (it + 2 < 16) issue((it + 2) << 5, (it + 2) % 3); // overwrite-safe: post-barrier
#pragma unroll
    for (int mt = 0; mt < 4; ++mt)
#pragma unroll
      for (int nt = 0; nt < 4; ++nt)
        acc[mt][nt] = __builtin_amdgcn_mfma_f32_16x16x32_bf16(af[mt], bfv[nt],
                                                              acc[mt][nt], 0, 0, 0);
  }
}
// C/D layout (verified m89/m91): col = lane&15, row = (lane>>4)*4 + reg.

// ---------------------------------------------------------------- weight transpose
// All segments: K = 512, N multiple of 64 -> no guards needed.
struct TEntry { const float* src; bf16* dst; int N, tile0, ntn; };
struct TArgs { TEntry e[11]; };

__global__ void k_transpose(TArgs a) {
  __shared__ float tile[64][65];
  int t = blockIdx.x;
  int ei = 0;
  while (ei < 10 && t >= a.e[ei + 1].tile0) ++ei;
  const TEntry E = a.e[ei];
  int lt = t - E.tile0;
  int tk = lt / E.ntn, tn = lt - tk * E.ntn;
  int k0 = tk << 6, n0 = tn << 6;
  int tid = threadIdx.x;
#pragma unroll
  for (int i = 0; i < 4; ++i) {
    int idx = tid + i * 256;                // 1024 float4 chunks
    int kk = idx >> 4, c4 = (idx & 15) << 2;
    const float4 v = *(const float4*)(E.src + (size_t)(k0 + kk) * E.N + n0 + c4);
    tile[c4 + 0][kk] = v.x; tile[c4 + 1][kk] = v.y;
    tile[c4 + 2][kk] = v.z; tile[c4 + 3][kk] = v.w;
  }
  __syncthreads();
#pragma unroll
  for (int i = 0; i < 4; ++i) {
    int idx = tid + i * 256;
    int nn = idx >> 4, k4 = (idx & 15) << 2;
    bf16x4 o;
    o[0] = (bf16)tile[nn][k4 + 0]; o[1] = (bf16)tile[nn][k4 + 1];
    o[2] = (bf16)tile[nn][k4 + 2]; o[3] = (bf16)tile[nn][k4 + 3];
    *(bf16x4*)(E.dst + (size_t)(n0 + nn) * 512 + k0 + k4) = o;
  }
}

// ---------------------------------------------------------------- bias gather
__global__ void k_prep(const float* ba, const float* bo, const float* bVr, const float* bVi,
                       const float* bBr, const float* bBi, const float* bD,
                       const float* bUr, const float* bUi, const float* bCr, const float* bCi,
                       float* bbigA, float* bbigB, float* bbigC) {
  int i = blockIdx.x * 256 + threadIdx.x;
  if (i < 22656) {
    float v;
    if (i < 256) v = ba[i];
    else if (i < 512) v = bo[i - 256];
    else if (i < 2560) v = bVr[i - 512];
    else if (i < 4608) v = bVi[i - 2560];
    else if (i < 12800) v = bBr[i - 4608];
    else if (i < 20992) v = bBi[i - 12800];
    else if (i < 22592) v = bD[i - 20992];
    else v = 0.f;
    bbigA[i] = v;
  }
  int j = i - 22656;
  if (j >= 0 && j < 4096) bbigB[j] = (j < 2048) ? bUr[j] : bUi[j - 2048];
  int m = i - (22656 + 4096);
  if (m >= 0 && m < 25600) bbigC[m] = (m < 12800) ? bCr[m] : bCi[m - 12800];
}

// ---------------------------------------------------------------- selector MLP (fp32)
__global__ void k_lin0(const float* __restrict__ zt, const float* __restrict__ dt,
                       const float* __restrict__ ut, const float* __restrict__ W0,
                       const float* __restrict__ b0, float* __restrict__ s0) {
  int i = blockIdx.x * 256 + threadIdx.x;      // 2048*128
  int b = i >> 7, c = i & 127;
  const float* w = W0 + c;
  const float* x = zt + (size_t)b * 512;
  float acc = b0[c];
#pragma unroll 4
  for (int k = 0; k < 512; ++k) acc = fmaf(x[k], w[(size_t)k * 128], acc);
  const float* u = ut + (size_t)b * 32;
#pragma unroll
  for (int k = 0; k < 32; ++k) acc = fmaf(u[k], w[(size_t)(512 + k) * 128], acc);
  acc = fmaf(dt[b], w[(size_t)544 * 128], acc);
  s0[i] = acc;
}

__global__ void k_stats(const float* __restrict__ s, float* __restrict__ mu,
                        float* __restrict__ rstd) {
  int c = blockIdx.x;                           // 128 columns
  float sm = 0.f, sq = 0.f;
  for (int r = threadIdx.x; r < 2048; r += 256) {
    float v = s[(size_t)r * 128 + c];
    sm += v; sq += v * v;
  }
#pragma unroll
  for (int o = 32; o >= 1; o >>= 1) { sm += __shfl_down(sm, o); sq += __shfl_down(sq, o); }
  __shared__ float red[8];
  int w = threadIdx.x >> 6;
  if ((threadIdx.x & 63) == 0) { red[w] = sm; red[4 + w] = sq; }
  __syncthreads();
  if (threadIdx.x == 0) {
    float S = red[0] + red[1] + red[2] + red[3];
    float Q = red[4] + red[5] + red[6] + red[7];
    float m = S * (1.f / 2048.f);
    float var = Q * (1.f / 2048.f) - m * m;    // biased var (training-mode BN)
    mu[c] = m;
    rstd[c] = rsqrtf(var + 1e-5f);
  }
}

__global__ void k_lin1(const float* __restrict__ s0, const float* __restrict__ mu,
                       const float* __restrict__ rstd, const float* __restrict__ g,
                       const float* __restrict__ be, const float* __restrict__ W1,
                       const float* __restrict__ b1, float* __restrict__ s1) {
  int i = blockIdx.x * 256 + threadIdx.x;      // 2048*128
  int b = i >> 7, c = i & 127;
  const float* w = W1 + c;
  const float* x = s0 + (size_t)b * 128;
  float acc = b1[c];
#pragma unroll 4
  for (int k = 0; k < 128; ++k) {
    float h = fmaxf(fmaf((x[k] - mu[k]) * rstd[k], g[k], be[k]), 0.f);
    acc = fmaf(h, w[(size_t)k * 128], acc);
  }
  s1[i] = acc;
}

__global__ void k_lin2(const float* __restrict__ s1, const float* __restrict__ mu,
                       const float* __restrict__ rstd, const float* __restrict__ g,
                       const float* __restrict__ be, const float* __restrict__ W2,
                       const float* __restrict__ b2, bf16* __restrict__ hz) {
  int i = blockIdx.x * 256 + threadIdx.x;      // 2048*512
  int b = i >> 9, c = i & 511;
  const float* w = W2 + c;
  const float* x = s1 + (size_t)b * 128;
  float acc = b2[c];
#pragma unroll 4
  for (int k = 0; k < 128; ++k) {
    float h = fmaxf(fmaf((x[k] - mu[k]) * rstd[k], g[k], be[k]), 0.f);
    acc = fmaf(h, w[(size_t)k * 512], acc);
  }
  hz[i] = (bf16)acc;
}

// ---------------------------------------------------------------- phase A GEMM
// columns: [0,256) a | [256,512) o | [512,2560) Vr | [2560,4608) Vi
//          [4608,12800) Br | [12800,20992) Bi | [20992,22592) D | pad to 22656
__global__ __launch_bounds__(256) void k_gemmA(
    const bf16* __restrict__ hz, const bf16* __restrict__ WT, const float* __restrict__ bias,
    const float* __restrict__ zt, const float* __restrict__ dt, const float* __restrict__ ut,
    float* __restrict__ pa, float* __restrict__ po,
    float* __restrict__ Bzr, float* __restrict__ Bzi,
    float* __restrict__ tbuf, float* __restrict__ ytout) {
  int m0, n0;
  if (!tile_map(177, m0, n0)) return;
  __shared__ __align__(16) bf16 lds[24576];
  f32x4 acc[4][4];
  gemm_p3(hz, WT, m0, n0, lds, acc);
  const int l = threadIdx.x & 63, w = threadIdx.x >> 6;
  const int wm = (w >> 1) << 6, wn = (w & 1) << 6;
  const int fr = l & 15, quad = l >> 4;
  const int ncol = n0 + wn;

  if (n0 < 512) {                                    // ---- a / o pre-acts
    float* dst = (n0 < 256) ? pa : po;
    int cb = ncol - ((n0 < 256) ? 0 : 256);
#pragma unroll
    for (int mt = 0; mt < 4; ++mt)
#pragma unroll
      for (int j = 0; j < 4; ++j) {
        int b = m0 + wm + mt * 16 + quad * 4 + j;
#pragma unroll
        for (int nt = 0; nt < 4; ++nt) {
          int n = ncol + nt * 16 + fr;
          dst[(size_t)b * 256 + (cb + nt * 16 + fr)] = acc[mt][nt][j] + bias[n];
        }
      }
  } else if (n0 < 4608) {                            // ---- V: t = conj(V)^T z
    const bool isVr = n0 < 2560;
#pragma unroll
    for (int mt = 0; mt < 4; ++mt)
#pragma unroll
      for (int j = 0; j < 4; ++j) {
        int b = m0 + wm + mt * 16 + quad * 4 + j;
        float cre = 0.f, cim = 0.f;
#pragma unroll
        for (int nt = 0; nt < 4; ++nt) {
          int n = ncol + nt * 16 + fr;
          float v = acc[mt][nt][j] + bias[n];
          int d = ((n - 512) & 2047) >> 3;
          float zr = zt[(size_t)b * 512 + d], zi = zt[(size_t)b * 512 + 256 + d];
          if (isVr) { cre += v * zr; cim += v * zi; }
          else      { cre += v * zi; cim -= v * zr; }
        }
        cre += __shfl_xor(cre, 8);
        cim += __shfl_xor(cim, 8);
        if ((l & 8) == 0) {
          int r = fr & 7;
          atomicAdd(&tbuf[((size_t)b * 8 + r) * 2 + 0], cre);
          atomicAdd(&tbuf[((size_t)b * 8 + r) * 2 + 1], cim);
        }
      }
  } else if (n0 < 20992) {                           // ---- B: Bz = Bt @ (ut*dt)
    const bool isBr = n0 < 12800;
    float* dst = isBr ? Bzr : Bzi;
#pragma unroll
    for (int mt = 0; mt < 4; ++mt)
#pragma unroll
      for (int j = 0; j < 4; ++j) {
        int b = m0 + wm + mt * 16 + quad * 4 + j;
        float dtb = dt[b];
#pragma unroll
        for (int g = 0; g < 2; ++g) {
          float s = 0.f;
#pragma unroll
          for (int h = 0; h < 2; ++h) {
            int nt = g * 2 + h;
            int n = ncol + nt * 16 + fr;
            int base = (n - 4608) & 8191;
            float v = acc[mt][nt][j] + bias[n];
            s += v * ut[(size_t)b * 32 + (base & 31)];
          }
          s *= dtb;
          s += __shfl_xor(s, 1); s += __shfl_xor(s, 2);
          s += __shfl_xor(s, 4); s += __shfl_xor(s, 8);
          if ((l & 15) == 0) {
            int d = (((ncol + g * 32) - 4608) & 8191) >> 5;
            dst[(size_t)b * 256 + d] = s;
          }
        }
      }
  } else {                                           // ---- D: yt init
#pragma unroll
    for (int mt = 0; mt < 4; ++mt)
#pragma unroll
      for (int j = 0; j < 4; ++j) {
        int b = m0 + wm + mt * 16 + quad * 4 + j;
        float dtb = dt[b];
#pragma unroll
        for (int g = 0; g < 2; ++g) {
          float s = 0.f;
#pragma unroll
          for (int h = 0; h < 2; ++h) {
            int nt = g * 2 + h;
            int n = ncol + nt * 16 + fr;
            int base = n - 20992;
            float v = acc[mt][nt][j] + bias[n];
            s += v * ut[(size_t)b * 32 + (base & 31)];
          }
          s *= dtb;
          s += __shfl_xor(s, 1); s += __shfl_xor(s, 2);
          s += __shfl_xor(s, 4); s += __shfl_xor(s, 8);
          int nn = ((ncol + g * 32) - 20992) >> 5;
          if ((l & 15) == 0 && nn < 50) ytout[(size_t)b * 50 + nn] = s;
        }
      }
  }
}

// ---------------------------------------------------------------- phase B GEMM (U)
__global__ __launch_bounds__(256) void k_gemmB(
    const bf16* __restrict__ hz, const bf16* __restrict__ WT, const float* __restrict__ bias,
    const float* __restrict__ tbuf, float* __restrict__ lr) {
  int m0, n0;
  if (!tile_map(32, m0, n0)) return;
  __shared__ __align__(16) bf16 lds[24576];
  f32x4 acc[4][4];
  gemm_p3(hz, WT, m0, n0, lds, acc);
  const int l = threadIdx.x & 63, w = threadIdx.x >> 6;
  const int wm = (w >> 1) << 6, wn = (w & 1) << 6;
  const int fr = l & 15, quad = l >> 4;
  const int ncol = n0 + wn;
  const bool isUr = n0 < 2048;
#pragma unroll
  for (int mt = 0; mt < 4; ++mt)
#pragma unroll
    for (int j = 0; j < 4; ++j) {
      int b = m0 + wm + mt * 16 + quad * 4 + j;
#pragma unroll
      for (int nt = 0; nt < 4; ++nt) {
        int n = ncol + nt * 16 + fr;
        int base = n & 2047;
        int r = base & 7, d = base >> 3;
        float v = acc[mt][nt][j] + bias[n];
        float tre = tbuf[((size_t)b * 8 + r) * 2], tim = tbuf[((size_t)b * 8 + r) * 2 + 1];
        float cre = isUr ? v * tre : -v * tim;
        float cim = isUr ? v * tim :  v * tre;
        cre += __shfl_xor(cre, 1); cre += __shfl_xor(cre, 2); cre += __shfl_xor(cre, 4);
        cim += __shfl_xor(cim, 1); cim += __shfl_xor(cim, 2); cim += __shfl_xor(cim, 4);
        if ((l & 7) == 0) {
          atomicAdd(&lr[((size_t)b * 256 + d) * 2 + 0], cre);
          atomicAdd(&lr[((size_t)b * 256 + d) * 2 + 1], cim);
        }
      }
    }
}

// ---------------------------------------------------------------- z_next assembly
__global__ void k_assembleZ(const float* __restrict__ zt, const float* __restrict__ pa,
                            const float* __restrict__ po, const float* __restrict__ Bzr,
                            const float* __restrict__ Bzi, const float* __restrict__ lr,
                            float* __restrict__ zout, float* __restrict__ znr,
                            float* __restrict__ zni) {
  int i = blockIdx.x * 256 + threadIdx.x;      // 2048*256
  int b = i >> 8, d = i & 255;
  float a = pa[i], o = po[i];
  float sp = fmaxf(a, 0.f) + log1pf(expf(-fabsf(a)));   // softplus, stable
  float mag = expf(-sp);
  float Lr = mag * cosf(o), Li = mag * sinf(o);
  float zr = zt[(size_t)b * 512 + d], zi = zt[(size_t)b * 512 + 256 + d];
  float re = fmaf(Lr, zr, -Li * zi) + Bzr[i] + lr[2 * i];
  float im = fmaf(Lr, zi,  Li * zr) + Bzi[i] + lr[2 * i + 1];
  zout[(size_t)b * 512 + d] = re;
  zout[(size_t)b * 512 + 256 + d] = im;
  znr[i] = re; zni[i] = im;
}

// ---------------------------------------------------------------- phase C GEMM (C)
__global__ __launch_bounds__(256) void k_gemmC(
    const bf16* __restrict__ hz, const bf16* __restrict__ WT, const float* __restrict__ bias,
    const float* __restrict__ znr, const float* __restrict__ zni, float* __restrict__ ytout) {
  int m0, n0;
  if (!tile_map(200, m0, n0)) return;
  __shared__ __align__(16) bf16 lds[24576];
  f32x4 acc[4][4];
  gemm_p3(hz, WT, m0, n0, lds, acc);
  const int l = threadIdx.x & 63, w = threadIdx.x >> 6;
  const int wm = (w >> 1) << 6, wn = (w & 1) << 6;
  const int fr = l & 15, quad = l >> 4;
  const int ncol = n0 + wn;
  const bool isCr = n0 < 12800;
  const int nb = ncol - (isCr ? 0 : 12800);
  const int nn = nb >> 8;
#pragma unroll
  for (int mt = 0; mt < 4; ++mt)
#pragma unroll
    for (int j = 0; j < 4; ++j) {
      int b = m0 + wm + mt * 16 + quad * 4 + j;
      float s = 0.f;
#pragma unroll
      for (int nt = 0; nt < 4; ++nt) {
        int n = ncol + nt * 16 + fr;
        int d = (nb + nt * 16 + fr) & 255;
        float v = acc[mt][nt][j] + bias[n];
        s += isCr ? v * znr[(size_t)b * 256 + d] : -(v * zni[(size_t)b * 256 + d]);
      }
      s += __shfl_xor(s, 1); s += __shfl_xor(s, 2);
      s += __shfl_xor(s, 4); s += __shfl_xor(s, 8);
      if ((l & 15) == 0) atomicAdd(&ytout[(size_t)b * 50 + nn], s);
    }
}

// ---------------------------------------------------------------- launch
extern "C" void kernel_launch(void* const* d_in, const int* in_sizes, int n_in,
                              void* d_out, int out_size, void* d_ws, size_t ws_size,
                              hipStream_t stream) {
  (void)in_sizes; (void)n_in; (void)out_size; (void)ws_size;
  const float* zt  = (const float*)d_in[0];
  const float* dt  = (const float*)d_in[1];
  const float* ut  = (const float*)d_in[2];
  const float* W0  = (const float*)d_in[3];  const float* b0  = (const float*)d_in[4];
  const float* W1  = (const float*)d_in[5];  const float* b1  = (const float*)d_in[6];
  const float* W2  = (const float*)d_in[7];  const float* b2  = (const float*)d_in[8];
  const float* Wa  = (const float*)d_in[9];  const float* ba  = (const float*)d_in[10];
  const float* Wo  = (const float*)d_in[11]; const float* bo  = (const float*)d_in[12];
  const float* WUr = (const float*)d_in[13]; const float* bUr = (const float*)d_in[14];
  const float* WUi = (const float*)d_in[15]; const float* bUi = (const float*)d_in[16];
  const float* WVr = (const float*)d_in[17]; const float* bVr = (const float*)d_in[18];
  const float* WVi = (const float*)d_in[19]; const float* bVi = (const float*)d_in[20];
  const float* WBr = (const float*)d_in[21]; const float* bBr = (const float*)d_in[22];
  const float* WBi = (const float*)d_in[23]; const float* bBi = (const float*)d_in[24];
  const float* WCr = (const float*)d_in[25]; const float* bCr = (const float*)d_in[26];
  const float* WCi = (const float*)d_in[27]; const float* bCi = (const float*)d_in[28];
  const float* WD  = (const float*)d_in[29]; const float* bD  = (const float*)d_in[30];
  const float* g0  = (const float*)d_in[31]; const float* be0 = (const float*)d_in[32];
  const float* g1  = (const float*)d_in[33]; const float* be1 = (const float*)d_in[34];

  char* ws = (char*)d_ws;
  bf16*  WTbig = (bf16*)(ws + 0);            // [22656, 512] bf16
  bf16*  WTU   = (bf16*)(ws + 23199744);     // [4096, 512]
  bf16*  WTC   = (bf16*)(ws + 27394048);     // [25600, 512]
  bf16*  hz    = (bf16*)(ws + 53608448);     // [2048, 512]
  float* s0    = (float*)(ws + 55705600);    // [2048, 128]
  float* s1    = (float*)(ws + 56754176);    // [2048, 128]
  float* mu0   = (float*)(ws + 57802752);
  float* rstd0 = mu0 + 128;
  float* mu1   = mu0 + 256;
  float* rstd1 = mu0 + 384;
  float* bbigA = (float*)(ws + 57804800);    // [22656]
  float* bbigB = (float*)(ws + 57895424);    // [4096]
  float* bbigC = (float*)(ws + 57911808);    // [25600]
  float* pa    = (float*)(ws + 58014208);    // [2048, 256]
  float* po    = (float*)(ws + 60111360);
  float* Bzr   = (float*)(ws + 62208512);
  float* Bzi   = (float*)(ws + 64305664);
  float* tbuf  = (float*)(ws + 66402816);    // [2048, 8, 2]
  float* lr    = (float*)(ws + 66533888);    // [2048, 256, 2]
  float* znr   = (float*)(ws + 70728192);
  float* zni   = (float*)(ws + 72825344);    // ends 74,922,496
  float* zout  = (float*)d_out;
  float* ytout = zout + 2048 * 512;

  k_prep<<<205, 256, 0, stream>>>(ba, bo, bVr, bVi, bBr, bBi, bD, bUr, bUi, bCr, bCi,
                                  bbigA, bbigB, bbigC);

  TArgs ta; int tile0 = 0; int idx = 0;
  auto add = [&](const float* src, bf16* dst, int N) {
    int ntn = N >> 6;
    ta.e[idx].src = src; ta.e[idx].dst = dst; ta.e[idx].N = N;
    ta.e[idx].tile0 = tile0; ta.e[idx].ntn = ntn;
    tile0 += ntn * 8; ++idx;
  };
  add(Wa,  WTbig + (size_t)0 * 512,     256);
  add(Wo,  WTbig + (size_t)256 * 512,   256);
  add(WVr, WTbig + (size_t)512 * 512,   2048);
  add(WVi, WTbig + (size_t)2560 * 512,  2048);
  add(WBr, WTbig + (size_t)4608 * 512,  8192);
  add(WBi, WTbig + (size_t)12800 * 512, 8192);
  add(WD,  WTbig + (size_t)20992 * 512, 1600);
  add(WUr, WTU,                         2048);
  add(WUi, WTU + (size_t)2048 * 512,    2048);
  add(WCr, WTC,                         12800);
  add(WCi, WTC + (size_t)12800 * 512,   12800);
  k_transpose<<<tile0, 256, 0, stream>>>(ta);

  hipMemsetAsync(tbuf, 0, 131072, stream);
  hipMemsetAsync(lr, 0, 4194304, stream);

  k_lin0<<<1024, 256, 0, stream>>>(zt, dt, ut, W0, b0, s0);
  k_stats<<<128, 256, 0, stream>>>(s0, mu0, rstd0);
  k_lin1<<<1024, 256, 0, stream>>>(s0, mu0, rstd0, g0, be0, W1, b1, s1);
  k_stats<<<128, 256, 0, stream>>>(s1, mu1, rstd1);
  k_lin2<<<4096, 256, 0, stream>>>(s1, mu1, rstd1, g1, be1, W2, b2, hz);

  // NT=177 -> pad to 184 n-tiles; invalid tiles early-exit before any barrier
  // (all waves of a block take the same branch -> no barrier divergence).
  k_gemmA<<<184 * 16, 256, 0, stream>>>(hz, WTbig, bbigA, zt, dt, ut,
                                        pa, po, Bzr, Bzi, tbuf, ytout);
  k_gemmB<<<32 * 16, 256, 0, stream>>>(hz, WTU, bbigB, tbuf, lr);
  k_assembleZ<<<2048, 256, 0, stream>>>(zt, pa, po, Bzr, Bzi, lr, zout, znr, zni);
  k_gemmC<<<200 * 16, 256, 0, stream>>>(hz, WTC, bbigC, znr, zni, ytout);
}